// Round 17
// baseline (97.919 us; speedup 1.0000x reference)
//
#include <hip/hip_runtime.h>

// VQVAE quantize.  x: [8,64,32,32] fp32, codebook: [8192,64] fp32.
// d_out (fp32, concat): [0,524288) quant_out | [524288] commit_loss |
//                       [524289] codebook_loss | [524290,532482) indices
//
// argmin via fp16x2 emulated-fp32 MFMA GEMM (3 terms):
//   v = h + m (2 fp16, exact to ~|v|*2^-23); dot ~= hh + hm + mh
//   score = dot - 0.5*e2[k]  (argmax score == argmin d2; absmax 0 R12-R16)
//
// R16 diagnosis: argmin pinned ~43us since R5 across all paradigms;
// MfmaUtil 21%, VALUBusy 25%, Occupancy 17% -> latency/occupancy-bound
// (MFMA content only ~6.6us). R17: SPLITS=64 (grid 2048, better rounds/
// tail overlap) + whole-split staged once (33.3 KB, same LDS) -> ONE
// barrier/block instead of 5. Compute = 2 x 4-tile clusters, outer loop
// unroll-pinned (R13: 8-tile unroll spills). R7: B via LDS. R6: no
// tight launch_bounds.

#define N_PTS   8192
#define K_CODES 8192
#define C_DIM   64
#define HWSZ    1024
#define QOUT_N  524288
#define SPLITS  64            // codes per split = 128, staged whole

// ---- workspace layout (bytes) ----
#define WS_XS    0            // u16 [2][8][8192][8]  = 2097152
#define WS_CBS   2097152      // u16 [2*8][8192][8]   = 2097152
#define WS_E2H   4194304      // float [8192]         = 32768
#define WS_PACK  4227072      // u64 [64][8192]       = 4194304
#define WS_PART  8421376      // float [1024]

typedef __attribute__((ext_vector_type(8))) short    short8;
typedef __attribute__((ext_vector_type(8))) _Float16 half8;
typedef __attribute__((ext_vector_type(4))) float    floatx4;

__device__ __forceinline__ half8 as_h8(short8 v) {
    return __builtin_bit_cast(half8, v);
}
__device__ __forceinline__ void split2(float v, unsigned short& h,
                                       unsigned short& m) {
    _Float16 hh = (_Float16)v;                     // RNE
    float r = v - (float)hh;
    _Float16 mm = (_Float16)r;
    h = __builtin_bit_cast(unsigned short, hh);
    m = __builtin_bit_cast(unsigned short, mm);
}
__device__ __forceinline__ void cp16(const void* g, void* l) {
    __builtin_amdgcn_global_load_lds(
        (const __attribute__((address_space(1))) void*)g,
        (__attribute__((address_space(3))) void*)l, 16, 0, 0);
}
__device__ __forceinline__ void cp4(const void* g, void* l) {
    __builtin_amdgcn_global_load_lds(
        (const __attribute__((address_space(1))) void*)g,
        (__attribute__((address_space(3))) void*)l, 4, 0, 0);
}

// ============================================================
// Kernel A: prep (no LDS, all coalesced).
//  blocks 0..31   : cb split + e2h (1 row/thread).
//  blocks 32..287 : x split, block=(b,g,quarter), 1 point/thread.
// Plane layout [p*8+g][n][8], p in {0=h,1=m}: 16B per
// (point|code, c-octet g) == one MFMA fragment k-group.
// ============================================================
__global__ __launch_bounds__(256)
void vq_prep_kernel(const float* __restrict__ x,
                    const float* __restrict__ cb,
                    unsigned short* __restrict__ xS,
                    unsigned short* __restrict__ cbS,
                    float* __restrict__ e2h)
{
    const int bx  = blockIdx.x;
    const int tid = threadIdx.x;

    if (bx < 32) {                           // ---- cb split + e2h ----
        const int k = bx * 256 + tid;
        const float* row = cb + k * C_DIM;
        float s = 0.0f;
        #pragma unroll
        for (int g = 0; g < 8; ++g) {
            float4 a = *(const float4*)(row + g * 8);
            float4 b = *(const float4*)(row + g * 8 + 4);
            float vv[8] = {a.x, a.y, a.z, a.w, b.x, b.y, b.z, b.w};
            unsigned short h8[8], m8[8];
            #pragma unroll
            for (int j = 0; j < 8; ++j) {
                s = fmaf(vv[j], vv[j], s);
                split2(vv[j], h8[j], m8[j]);
            }
            *(uint4*)(cbS + ((size_t)(0 * 8 + g) * 8192 + k) * 8) = *(const uint4*)h8;
            *(uint4*)(cbS + ((size_t)(1 * 8 + g) * 8192 + k) * 8) = *(const uint4*)m8;
        }
        e2h[k] = 0.5f * s;
    } else {                                 // ---- x split ----
        const int u = bx - 32;               // 0..255
        const int b = u >> 5, g = (u >> 2) & 7, q = u & 3;
        const int hw = q * 256 + tid;
        const float* xb = x + (size_t)(b * C_DIM + g * 8) * HWSZ + hw;
        unsigned short h8[8], m8[8];
        #pragma unroll
        for (int cq = 0; cq < 8; ++cq)
            split2(xb[cq * HWSZ], h8[cq], m8[cq]);
        const size_t n = (size_t)b * 1024 + hw;
        *(uint4*)(xS + ((size_t)(0 * 8 + g) * 8192 + n) * 8) = *(const uint4*)h8;
        *(uint4*)(xS + ((size_t)(1 * 8 + g) * 8192 + n) * 8) = *(const uint4*)m8;
    }
}

// ============================================================
// Kernel B: argmin via 16x16x32 f16 MFMA. grid (32 m-blocks,
// 64 splits) = 2048 blocks x 256 threads; LDS 33.3 KB single
// buffer holding the block's whole 128-code split -> ONE barrier.
// Wave owns 64 points (4 tiles of 16); A-frags in regs (64 VGPR).
// After the barrier: 2 x (4-tile unrolled cluster), outer loop
// unroll-pinned (R13 register lesson). Final __shfl_xor reduce.
// Layouts (verified m89/m91/m120): A[m=lane&15][k=quad*8+j],
// B[k=quad*8+j][n=lane&15], C: col=lane&15, row=quad*4+reg.
// ============================================================
#define SEG_SHORTS 1024       // 128 codes * 8 shorts per (p,g) segment
#define NSEGS      16         // 2 planes x 8 octets
#define BUF_SHORTS 16640      // 16*1024 + 256 (e2 slice: 128 floats)

__device__ __forceinline__ void computeTile(const half8 af[4][2][2],
                                            const unsigned short* __restrict__ bsrc,
                                            int lc, int quad, int code,
                                            float bestv[4][4], int besti[4][4])
{
    half8 bf[2][2];
    #pragma unroll
    for (int p = 0; p < 2; ++p)
        #pragma unroll
        for (int s = 0; s < 2; ++s) {
            int seg = p * 8 + s * 4 + quad;
            bf[p][s] = as_h8(*(const short8*)(bsrc + seg * SEG_SHORTS + lc * 8));
        }
    float me2 = -((const float*)(bsrc + NSEGS * SEG_SHORTS))[lc];

    floatx4 acc[4];
    #pragma unroll
    for (int t = 0; t < 4; ++t) acc[t] = (floatx4){me2, me2, me2, me2};

    #pragma unroll
    for (int s = 0; s < 2; ++s) {
        #pragma unroll
        for (int t = 0; t < 4; ++t)
            acc[t] = __builtin_amdgcn_mfma_f32_16x16x32_f16(af[t][0][s], bf[0][s], acc[t], 0, 0, 0); // hh
        #pragma unroll
        for (int t = 0; t < 4; ++t)
            acc[t] = __builtin_amdgcn_mfma_f32_16x16x32_f16(af[t][0][s], bf[1][s], acc[t], 0, 0, 0); // hm
        #pragma unroll
        for (int t = 0; t < 4; ++t)
            acc[t] = __builtin_amdgcn_mfma_f32_16x16x32_f16(af[t][1][s], bf[0][s], acc[t], 0, 0, 0); // mh
    }

    #pragma unroll
    for (int t = 0; t < 4; ++t)
        #pragma unroll
        for (int r = 0; r < 4; ++r) {
            float sc = acc[t][r];
            bool gt = sc > bestv[t][r];        // strict: earlier code wins ties
            bestv[t][r] = gt ? sc   : bestv[t][r];
            besti[t][r] = gt ? code : besti[t][r];
        }
}

__global__ __launch_bounds__(256, 2)
void vq_argmin_kernel(const unsigned short* __restrict__ xS,
                      const unsigned short* __restrict__ cbS,
                      const float* __restrict__ e2h,
                      unsigned long long* __restrict__ packedS)
{
    __shared__ __align__(16) unsigned short sBuf[BUF_SHORTS];   // 33280 B

    const int tid   = threadIdx.x;
    const int lane  = tid & 63;
    const int w     = tid >> 6;
    const int col   = lane & 15;
    const int quad  = lane >> 4;
    const int mb    = blockIdx.x;        // 0..31
    const int split = blockIdx.y;        // 0..63
    const int m0    = mb * 256 + w * 64;
    const int nb0   = split * 128;

    // stage the whole 128-code split: 16 segs x 2KB + e2 slice.
    // f = tid + i*256: seg = f>>7 wave-uniform; l = f&127 ->
    // wave-uniform LDS base + lane*16 (compliant).
    #pragma unroll
    for (int i = 0; i < 8; ++i) {
        int f   = tid + i * 256;             // 0..2047
        int seg = f >> 7;
        int l   = f & 127;
        cp16(cbS + ((size_t)seg * 8192 + nb0 + l) * 8,
             sBuf + seg * SEG_SHORTS + l * 8);
    }
    if (tid < 128)
        cp4(e2h + nb0 + tid, (float*)(sBuf + NSEGS * SEG_SHORTS) + tid);

    // A fragments: 4 tiles x 2 planes x 2 ksteps (64 VGPRs)
    half8 af[4][2][2];
    #pragma unroll
    for (int t = 0; t < 4; ++t) {
        int pt = m0 + t * 16 + col;
        #pragma unroll
        for (int p = 0; p < 2; ++p)
            #pragma unroll
            for (int s = 0; s < 2; ++s) {
                int g = s * 4 + quad;
                af[t][p][s] = as_h8(*(const short8*)(xS + ((size_t)(p * 8 + g) * 8192 + pt) * 8));
            }
    }

    float bestv[4][4];
    int   besti[4][4];
    #pragma unroll
    for (int t = 0; t < 4; ++t)
        #pragma unroll
        for (int r = 0; r < 4; ++r) {
            bestv[t][r] = __uint_as_float(0xFF800000u);  // -inf
            besti[t][r] = 0;
        }

    __syncthreads();                          // the ONE barrier: split staged

    #pragma unroll 1                          // keep R16's 4-tile register shape
    for (int half = 0; half < 2; ++half) {
        #pragma unroll
        for (int tl = 0; tl < 4; ++tl) {
            int lc = half * 64 + tl * 16 + col;
            computeTile(af, sBuf, lc, quad, nb0 + lc, bestv, besti);
        }
    }

    // final reduce over the 16 col-candidates per point, in-register:
    // per (t,r), u64-min across the 16 col lanes of each quad group
    // (xor masks 1,2,4,8 stay within the group). Lane with col==t*4+r
    // owns pair (t,r) and writes point m0 + t*16 + quad*4 + r.
    unsigned long long own = 0;
    #pragma unroll
    for (int t = 0; t < 4; ++t)
        #pragma unroll
        for (int r = 0; r < 4; ++r) {
            unsigned u = __float_as_uint(-bestv[t][r]);   // key ascending
            u = ((int)u < 0) ? ~u : (u | 0x80000000u);
            unsigned long long p = ((unsigned long long)u << 32) | (unsigned)besti[t][r];
            #pragma unroll
            for (int msk = 1; msk < 16; msk <<= 1) {
                unsigned long long q = __shfl_xor(p, msk, 64);
                p = (q < p) ? q : p;
            }
            own = (col == t * 4 + r) ? p : own;
        }
    const int mpt = m0 + (col >> 2) * 16 + quad * 4 + (col & 3);
    packedS[(size_t)split * N_PTS + mpt] = own;
}

// ============================================================
// Kernel C: gather. 256 blocks x 256; block owns 32 points,
// 8 threads/point. Phase 1: thread (p=tid&31, sg=tid>>5) reduces
// split slots sg*8..sg*8+7 -> sred[8][32]. Phase 2: every thread
// combines the 8 partials. Phase 3: thread handles channels
// sg*8..sg*8+7, fully coalesced; per-wave loss partials.
// ============================================================
__global__ __launch_bounds__(256)
void vq_gather_kernel(const float* __restrict__ x,
                      const float* __restrict__ cb,
                      const unsigned long long* __restrict__ packedS,
                      float* __restrict__ out,
                      float* __restrict__ part)
{
    __shared__ unsigned long long sred[8][32];
    const int tid = threadIdx.x;
    const int p   = tid & 31;
    const int sg  = tid >> 5;           // 0..7
    const int n0  = blockIdx.x * 32;
    const int n   = n0 + p;

    {
        unsigned long long v = packedS[(size_t)(sg * 8) * N_PTS + n];
        #pragma unroll
        for (int s = 1; s < 8; ++s) {
            unsigned long long q = packedS[(size_t)(sg * 8 + s) * N_PTS + n];
            v = (q < v) ? q : v;
        }
        sred[sg][p] = v;
    }
    __syncthreads();

    unsigned long long v = sred[0][p];
    #pragma unroll
    for (int s = 1; s < 8; ++s) {
        unsigned long long q = sred[s][p];
        v = (q < v) ? q : v;
    }
    const int idx = (int)(v & 0xFFFFFFFFull);
    if (tid < 32) out[QOUT_N + 2 + n0 + tid] = (float)idx;

    const int c0  = sg * 8;
    const int b   = n >> 10;
    const int hw  = n & 1023;
    const float* xb = x   + (size_t)b * (C_DIM * HWSZ) + hw;
    float*       ob = out + (size_t)b * (C_DIM * HWSZ) + hw;

    float s = 0.0f;
    #pragma unroll
    for (int c4 = 0; c4 < 2; ++c4) {
        float4 q = *(const float4*)(cb + (size_t)idx * C_DIM + c0 + c4 * 4);
        float qa[4] = {q.x, q.y, q.z, q.w};
        #pragma unroll
        for (int j = 0; j < 4; ++j) {
            int c = c0 + c4 * 4 + j;
            float xv = xb[c * HWSZ];
            float d  = qa[j] - xv;          // quant - x (reference rounding)
            s = fmaf(d, d, s);
            ob[c * HWSZ] = xv + d;          // straight-through: x + (q - x)
        }
    }

    #pragma unroll
    for (int off = 32; off > 0; off >>= 1) s += __shfl_down(s, off, 64);
    if ((tid & 63) == 0) part[blockIdx.x * 4 + (tid >> 6)] = s;
}

// ============================================================
// Kernel D: final loss reduction (1024 partials -> 2 scalars).
// ============================================================
__global__ __launch_bounds__(256)
void vq_final_kernel(const float* __restrict__ part, float* __restrict__ out)
{
    __shared__ float w[4];
    float s = part[threadIdx.x] + part[threadIdx.x + 256]
            + part[threadIdx.x + 512] + part[threadIdx.x + 768];
    #pragma unroll
    for (int off = 32; off > 0; off >>= 1) s += __shfl_down(s, off, 64);
    if ((threadIdx.x & 63) == 0) w[threadIdx.x >> 6] = s;
    __syncthreads();
    if (threadIdx.x == 0) {
        float m = (w[0] + w[1] + w[2] + w[3]) * (1.0f / (float)QOUT_N);
        out[QOUT_N]     = m;   // commitment_loss
        out[QOUT_N + 1] = m;   // codebook_loss
    }
}

extern "C" void kernel_launch(void* const* d_in, const int* in_sizes, int n_in,
                              void* d_out, int out_size, void* d_ws, size_t ws_size,
                              hipStream_t stream)
{
    const float* x  = (const float*)d_in[0];   // [8,64,32,32]
    const float* cb = (const float*)d_in[1];   // [8192,64]
    float* out = (float*)d_out;
    char*  ws  = (char*)d_ws;
    (void)ws_size;

    unsigned short* xS  = (unsigned short*)(ws + WS_XS);
    unsigned short* cbS = (unsigned short*)(ws + WS_CBS);
    float* e2h = (float*)(ws + WS_E2H);
    unsigned long long* packedS = (unsigned long long*)(ws + WS_PACK);
    float* part = (float*)(ws + WS_PART);

    vq_prep_kernel<<<288, 256, 0, stream>>>(x, cb, xS, cbS, e2h);
    vq_argmin_kernel<<<dim3(N_PTS / 256, SPLITS), 256, 0, stream>>>(xS, cbS, e2h, packedS);
    vq_gather_kernel<<<256, 256, 0, stream>>>(x, cb, packedS, out, part);
    vq_final_kernel<<<1, 256, 0, stream>>>(part, out);
}

// Round 18
// 90.315 us; speedup vs baseline: 1.0842x; 1.0842x over previous
//
#include <hip/hip_runtime.h>

// VQVAE quantize.  x: [8,64,32,32] fp32, codebook: [8192,64] fp32.
// d_out (fp32, concat): [0,524288) quant_out | [524288] commit_loss |
//                       [524289] codebook_loss | [524290,532482) indices
//
// argmin via fp16x2 emulated-fp32 MFMA GEMM (3 terms):
//   v = h + m (2 fp16, exact to ~|v|*2^-23); dot ~= hh + hm + mh
//   score = dot - 0.5*e2[k]  (argmax score == argmin d2; absmax 0 R12-R17)
//
// R17 diagnosis: the R5-R17 ~43us argmin wall is L2 LINE-REQUEST traffic:
// total reads = (SPLITS + grid_x) x 2 MB. R16 = 128 MB = 2.1M lines at
// ~20-29 lines/cyc TCC service = 30-43us = the wall. R18: SQUARE tiles
// 512 pts x 512 codes, grid (16,16) x 512 thr -> (16+16)x2 = 64 MB, 2x
// less traffic. Inner structure = R14/R16 verbatim (64-code chunks,
// 33.3 KB dbuf, prefetch, 4-tile clusters — R13: never unroll 8 tiles).
// R7: B via LDS. R6: no tight launch_bounds.

#define N_PTS   8192
#define K_CODES 8192
#define C_DIM   64
#define HWSZ    1024
#define QOUT_N  524288
#define SPLITS  16            // codes per split = 512 = 8 chunks of 64

// ---- workspace layout (bytes) ----
#define WS_XS    0            // u16 [2][8][8192][8]  = 2097152
#define WS_CBS   2097152      // u16 [2*8][8192][8]   = 2097152
#define WS_E2H   4194304      // float [8192]         = 32768
#define WS_PACK  4227072      // u64 [16][8192]       = 1048576
#define WS_PART  5275648      // float [1024]

typedef __attribute__((ext_vector_type(8))) short    short8;
typedef __attribute__((ext_vector_type(8))) _Float16 half8;
typedef __attribute__((ext_vector_type(4))) float    floatx4;

__device__ __forceinline__ half8 as_h8(short8 v) {
    return __builtin_bit_cast(half8, v);
}
__device__ __forceinline__ void split2(float v, unsigned short& h,
                                       unsigned short& m) {
    _Float16 hh = (_Float16)v;                     // RNE
    float r = v - (float)hh;
    _Float16 mm = (_Float16)r;
    h = __builtin_bit_cast(unsigned short, hh);
    m = __builtin_bit_cast(unsigned short, mm);
}
__device__ __forceinline__ void cp16(const void* g, void* l) {
    __builtin_amdgcn_global_load_lds(
        (const __attribute__((address_space(1))) void*)g,
        (__attribute__((address_space(3))) void*)l, 16, 0, 0);
}
__device__ __forceinline__ void cp4(const void* g, void* l) {
    __builtin_amdgcn_global_load_lds(
        (const __attribute__((address_space(1))) void*)g,
        (__attribute__((address_space(3))) void*)l, 4, 0, 0);
}

// ============================================================
// Kernel A: prep (no LDS, all coalesced).
//  blocks 0..31   : cb split + e2h (1 row/thread).
//  blocks 32..287 : x split, block=(b,g,quarter), 1 point/thread.
// Plane layout [p*8+g][n][8], p in {0=h,1=m}: 16B per
// (point|code, c-octet g) == one MFMA fragment k-group.
// ============================================================
__global__ __launch_bounds__(256)
void vq_prep_kernel(const float* __restrict__ x,
                    const float* __restrict__ cb,
                    unsigned short* __restrict__ xS,
                    unsigned short* __restrict__ cbS,
                    float* __restrict__ e2h)
{
    const int bx  = blockIdx.x;
    const int tid = threadIdx.x;

    if (bx < 32) {                           // ---- cb split + e2h ----
        const int k = bx * 256 + tid;
        const float* row = cb + k * C_DIM;
        float s = 0.0f;
        #pragma unroll
        for (int g = 0; g < 8; ++g) {
            float4 a = *(const float4*)(row + g * 8);
            float4 b = *(const float4*)(row + g * 8 + 4);
            float vv[8] = {a.x, a.y, a.z, a.w, b.x, b.y, b.z, b.w};
            unsigned short h8[8], m8[8];
            #pragma unroll
            for (int j = 0; j < 8; ++j) {
                s = fmaf(vv[j], vv[j], s);
                split2(vv[j], h8[j], m8[j]);
            }
            *(uint4*)(cbS + ((size_t)(0 * 8 + g) * 8192 + k) * 8) = *(const uint4*)h8;
            *(uint4*)(cbS + ((size_t)(1 * 8 + g) * 8192 + k) * 8) = *(const uint4*)m8;
        }
        e2h[k] = 0.5f * s;
    } else {                                 // ---- x split ----
        const int u = bx - 32;               // 0..255
        const int b = u >> 5, g = (u >> 2) & 7, q = u & 3;
        const int hw = q * 256 + tid;
        const float* xb = x + (size_t)(b * C_DIM + g * 8) * HWSZ + hw;
        unsigned short h8[8], m8[8];
        #pragma unroll
        for (int cq = 0; cq < 8; ++cq)
            split2(xb[cq * HWSZ], h8[cq], m8[cq]);
        const size_t n = (size_t)b * 1024 + hw;
        *(uint4*)(xS + ((size_t)(0 * 8 + g) * 8192 + n) * 8) = *(const uint4*)h8;
        *(uint4*)(xS + ((size_t)(1 * 8 + g) * 8192 + n) * 8) = *(const uint4*)m8;
    }
}

// ============================================================
// Kernel B: argmin via 16x16x32 f16 MFMA. grid (16 m-blocks,
// 16 splits) = 256 blocks x 512 threads (8 waves). Block tile
// 512 pts x 512 codes (square -> min L2 traffic). Wave owns 64
// points (4 tiles of 16); A-frags in regs (64 VGPR). Per 64-code
// chunk: prefetch next into the other LDS buffer (async, no VGPR
// cost), compute 4 tiles x 12 MFMA, one barrier. 8 chunks/split.
// Final reduce via __shfl_xor u64 min.
// Layouts (verified m89/m91/m120): A[m=lane&15][k=quad*8+j],
// B[k=quad*8+j][n=lane&15], C: col=lane&15, row=quad*4+reg.
// ============================================================
#define SEG_SHORTS 512        // 64 codes * 8 shorts per (p,g) segment
#define NSEGS      16         // 2 planes x 8 octets
#define BUF_SHORTS 8320       // 16*512 + 128 (e2 slice: 64 floats)

__device__ __forceinline__ void computeTile(const half8 af[4][2][2],
                                            const unsigned short* __restrict__ bsrc,
                                            int tl, int quad, int col, int code,
                                            float bestv[4][4], int besti[4][4])
{
    half8 bf[2][2];
    #pragma unroll
    for (int p = 0; p < 2; ++p)
        #pragma unroll
        for (int s = 0; s < 2; ++s) {
            int seg = p * 8 + s * 4 + quad;
            bf[p][s] = as_h8(*(const short8*)(bsrc + seg * SEG_SHORTS + (tl * 16 + col) * 8));
        }
    float me2 = -((const float*)(bsrc + NSEGS * SEG_SHORTS))[tl * 16 + col];

    floatx4 acc[4];
    #pragma unroll
    for (int t = 0; t < 4; ++t) acc[t] = (floatx4){me2, me2, me2, me2};

    #pragma unroll
    for (int s = 0; s < 2; ++s) {
        #pragma unroll
        for (int t = 0; t < 4; ++t)
            acc[t] = __builtin_amdgcn_mfma_f32_16x16x32_f16(af[t][0][s], bf[0][s], acc[t], 0, 0, 0); // hh
        #pragma unroll
        for (int t = 0; t < 4; ++t)
            acc[t] = __builtin_amdgcn_mfma_f32_16x16x32_f16(af[t][0][s], bf[1][s], acc[t], 0, 0, 0); // hm
        #pragma unroll
        for (int t = 0; t < 4; ++t)
            acc[t] = __builtin_amdgcn_mfma_f32_16x16x32_f16(af[t][1][s], bf[0][s], acc[t], 0, 0, 0); // mh
    }

    #pragma unroll
    for (int t = 0; t < 4; ++t)
        #pragma unroll
        for (int r = 0; r < 4; ++r) {
            float sc = acc[t][r];
            bool gt = sc > bestv[t][r];        // strict: earlier code wins ties
            bestv[t][r] = gt ? sc   : bestv[t][r];
            besti[t][r] = gt ? code : besti[t][r];
        }
}

__global__ __launch_bounds__(512, 1)
void vq_argmin_kernel(const unsigned short* __restrict__ xS,
                      const unsigned short* __restrict__ cbS,
                      const float* __restrict__ e2h,
                      unsigned long long* __restrict__ packedS)
{
    __shared__ __align__(16) unsigned short sBuf[2][BUF_SHORTS];  // 33280 B

    const int tid   = threadIdx.x;       // 0..511
    const int lane  = tid & 63;
    const int w     = tid >> 6;          // 0..7
    const int col   = lane & 15;
    const int quad  = lane >> 4;
    const int mb    = blockIdx.x;        // 0..15
    const int split = blockIdx.y;        // 0..15
    const int m0    = mb * 512 + w * 64;
    const int nb0   = split * 512;

    // A fragments: 4 tiles x 2 planes x 2 ksteps (64 VGPRs)
    half8 af[4][2][2];
    #pragma unroll
    for (int t = 0; t < 4; ++t) {
        int pt = m0 + t * 16 + col;
        #pragma unroll
        for (int p = 0; p < 2; ++p)
            #pragma unroll
            for (int s = 0; s < 2; ++s) {
                int g = s * 4 + quad;
                af[t][p][s] = as_h8(*(const short8*)(xS + ((size_t)(p * 8 + g) * 8192 + pt) * 8));
            }
    }

    float bestv[4][4];
    int   besti[4][4];
    #pragma unroll
    for (int t = 0; t < 4; ++t)
        #pragma unroll
        for (int r = 0; r < 4; ++r) {
            bestv[t][r] = __uint_as_float(0xFF800000u);  // -inf
            besti[t][r] = 0;
        }

    // async stage of one 64-code chunk: 16 segs x 1KB + e2 slice.
    // 512 threads: f = tid + i*512 (i<2); seg = f>>6 wave-uniform,
    // l = f&63 = lane -> wave-uniform LDS base + lane*16 (compliant).
    auto stage = [&](int k0, int buf) {
        unsigned short* dst = &sBuf[buf][0];
        #pragma unroll
        for (int i = 0; i < 2; ++i) {
            int f   = tid + i * 512;         // 0..1023
            int seg = f >> 6;
            int l   = f & 63;
            cp16(cbS + ((size_t)seg * 8192 + k0 + l) * 8,
                 dst + seg * SEG_SHORTS + l * 8);
        }
        if (tid < 64)
            cp4(e2h + k0 + tid, (float*)(dst + NSEGS * SEG_SHORTS) + tid);
    };

    stage(nb0, 0);
    __syncthreads();                          // chunk 0 staged

    for (int ch = 0; ch < 8; ++ch) {
        if (ch + 1 < 8) stage(nb0 + (ch + 1) * 64, (ch + 1) & 1);
        const unsigned short* bsrc = &sBuf[ch & 1][0];
        #pragma unroll
        for (int tl = 0; tl < 4; ++tl)
            computeTile(af, bsrc, tl, quad, col,
                        nb0 + ch * 64 + tl * 16 + col, bestv, besti);
        __syncthreads();    // reads of ch done + prefetch ch+1 landed
    }

    // final reduce over the 16 col-candidates per point, in-register:
    // per (t,r), u64-min across the 16 col lanes of each quad group
    // (xor masks 1,2,4,8 stay within the group). Lane with col==t*4+r
    // owns pair (t,r) and writes point m0 + t*16 + quad*4 + r.
    unsigned long long own = 0;
    #pragma unroll
    for (int t = 0; t < 4; ++t)
        #pragma unroll
        for (int r = 0; r < 4; ++r) {
            unsigned u = __float_as_uint(-bestv[t][r]);   // key ascending
            u = ((int)u < 0) ? ~u : (u | 0x80000000u);
            unsigned long long p = ((unsigned long long)u << 32) | (unsigned)besti[t][r];
            #pragma unroll
            for (int msk = 1; msk < 16; msk <<= 1) {
                unsigned long long q = __shfl_xor(p, msk, 64);
                p = (q < p) ? q : p;
            }
            own = (col == t * 4 + r) ? p : own;
        }
    const int mpt = m0 + (col >> 2) * 16 + quad * 4 + (col & 3);
    packedS[(size_t)split * N_PTS + mpt] = own;
}

// ============================================================
// Kernel C: gather. 256 blocks x 256; block owns 32 points,
// 8 threads/point. Phase 1: thread (p=tid&31, sg=tid>>5) reduces
// split slots {sg*2, sg*2+1} -> sred[8][32]. Phase 2: every
// thread combines the 8 partials. Phase 3: thread handles
// channels sg*8..sg*8+7, fully coalesced; per-wave loss partials.
// ============================================================
__global__ __launch_bounds__(256)
void vq_gather_kernel(const float* __restrict__ x,
                      const float* __restrict__ cb,
                      const unsigned long long* __restrict__ packedS,
                      float* __restrict__ out,
                      float* __restrict__ part)
{
    __shared__ unsigned long long sred[8][32];
    const int tid = threadIdx.x;
    const int p   = tid & 31;
    const int sg  = tid >> 5;           // 0..7
    const int n0  = blockIdx.x * 32;
    const int n   = n0 + p;

    {
        unsigned long long v = packedS[(size_t)(sg * 2) * N_PTS + n];
        unsigned long long q = packedS[(size_t)(sg * 2 + 1) * N_PTS + n];
        sred[sg][p] = (q < v) ? q : v;
    }
    __syncthreads();

    unsigned long long v = sred[0][p];
    #pragma unroll
    for (int s = 1; s < 8; ++s) {
        unsigned long long q = sred[s][p];
        v = (q < v) ? q : v;
    }
    const int idx = (int)(v & 0xFFFFFFFFull);
    if (tid < 32) out[QOUT_N + 2 + n0 + tid] = (float)idx;

    const int c0  = sg * 8;
    const int b   = n >> 10;
    const int hw  = n & 1023;
    const float* xb = x   + (size_t)b * (C_DIM * HWSZ) + hw;
    float*       ob = out + (size_t)b * (C_DIM * HWSZ) + hw;

    float s = 0.0f;
    #pragma unroll
    for (int c4 = 0; c4 < 2; ++c4) {
        float4 q = *(const float4*)(cb + (size_t)idx * C_DIM + c0 + c4 * 4);
        float qa[4] = {q.x, q.y, q.z, q.w};
        #pragma unroll
        for (int j = 0; j < 4; ++j) {
            int c = c0 + c4 * 4 + j;
            float xv = xb[c * HWSZ];
            float d  = qa[j] - xv;          // quant - x (reference rounding)
            s = fmaf(d, d, s);
            ob[c * HWSZ] = xv + d;          // straight-through: x + (q - x)
        }
    }

    #pragma unroll
    for (int off = 32; off > 0; off >>= 1) s += __shfl_down(s, off, 64);
    if ((tid & 63) == 0) part[blockIdx.x * 4 + (tid >> 6)] = s;
}

// ============================================================
// Kernel D: final loss reduction (1024 partials -> 2 scalars).
// ============================================================
__global__ __launch_bounds__(256)
void vq_final_kernel(const float* __restrict__ part, float* __restrict__ out)
{
    __shared__ float w[4];
    float s = part[threadIdx.x] + part[threadIdx.x + 256]
            + part[threadIdx.x + 512] + part[threadIdx.x + 768];
    #pragma unroll
    for (int off = 32; off > 0; off >>= 1) s += __shfl_down(s, off, 64);
    if ((threadIdx.x & 63) == 0) w[threadIdx.x >> 6] = s;
    __syncthreads();
    if (threadIdx.x == 0) {
        float m = (w[0] + w[1] + w[2] + w[3]) * (1.0f / (float)QOUT_N);
        out[QOUT_N]     = m;   // commitment_loss
        out[QOUT_N + 1] = m;   // codebook_loss
    }
}

extern "C" void kernel_launch(void* const* d_in, const int* in_sizes, int n_in,
                              void* d_out, int out_size, void* d_ws, size_t ws_size,
                              hipStream_t stream)
{
    const float* x  = (const float*)d_in[0];   // [8,64,32,32]
    const float* cb = (const float*)d_in[1];   // [8192,64]
    float* out = (float*)d_out;
    char*  ws  = (char*)d_ws;
    (void)ws_size;

    unsigned short* xS  = (unsigned short*)(ws + WS_XS);
    unsigned short* cbS = (unsigned short*)(ws + WS_CBS);
    float* e2h = (float*)(ws + WS_E2H);
    unsigned long long* packedS = (unsigned long long*)(ws + WS_PACK);
    float* part = (float*)(ws + WS_PART);

    vq_prep_kernel<<<288, 256, 0, stream>>>(x, cb, xS, cbS, e2h);
    vq_argmin_kernel<<<dim3(16, SPLITS), 512, 0, stream>>>(xS, cbS, e2h, packedS);
    vq_gather_kernel<<<256, 256, 0, stream>>>(x, cb, packedS, out, part);
    vq_final_kernel<<<1, 256, 0, stream>>>(part, out);
}